// Round 12
// baseline (1726.807 us; speedup 1.0000x reference)
//
#include <hip/hip_runtime.h>

typedef unsigned short ushort_t;
typedef unsigned int uint_t;
typedef unsigned long long ull_t;
typedef __attribute__((ext_vector_type(8))) short short8;
typedef __attribute__((ext_vector_type(4))) float f32x4;

#define B_ 1024
#define N_ 64
#define H_ 128
#define NT 256

// bf16 weight-image element offsets
#define IMG_WI 0
#define IMG_WJ 16384
#define IMG_UW 32768
#define IMG_GS 49152
#define IMG_FT 65536
#define IMG_FB 81920
#define IMG_C1 98304
#define IMG_C2 163840
#define IMG_GMT 229376
#define IMG_RW 245760
#define IMG_L 249856
#define IMG_FO 999424
#define WS_WEIGHTS (2u*1024u*1024u)
#define KNN_STRIDE 12288u

__device__ __forceinline__ ushort_t f2bf(float f) {
    uint_t u = __float_as_uint(f);
    return (ushort_t)((u + 0x7fffu + ((u >> 16) & 1u)) >> 16);
}
__device__ __forceinline__ float bf2f(ushort_t u) {
    union { uint_t i; float f; } v; v.i = ((uint_t)u) << 16; return v.f;
}
__device__ __forceinline__ float siluf(float x) { return x / (1.0f + __expf(-x)); }

// LDS swizzle: 16B-chunk c of row m stored at chunk c ^ (m&7)
__device__ __forceinline__ int sidx(int m, int k) {
    return m * H_ + (((k >> 3) ^ (m & 7)) << 3) + (k & 7);
}
__device__ __forceinline__ int fragoff(int m, int ch) {
    return m * H_ + ((ch ^ (m & 7)) << 3);
}

// ========== preamble 1: f32 weights -> transposed bf16 images ==============
extern "C" __global__ __launch_bounds__(256)
void convert_weights(const float* __restrict__ msg_W, const float* __restrict__ upd_W,
                     const float* __restrict__ gself_W, const float* __restrict__ fus_W,
                     const float* __restrict__ cb_W1, const float* __restrict__ cb_W2,
                     const float* __restrict__ gmean_W, const float* __restrict__ fo_W1,
                     ushort_t* __restrict__ wimg)
{
    const int g = blockIdx.x;
    if (g >= 244) {
        int st = g - 244;
        ushort_t* dst = wimg + IMG_FO + st * 4096;
        for (int e = 0; e < 16; ++e) {
            int q = threadIdx.x * 16 + e;
            int n = q >> 7, k = q & 127;
            dst[q] = f2bf(fo_W1[(size_t)k * 128 + st * 32 + n]);
        }
        return;
    }
    const int l = g / 61, r = g - l * 61;
    ushort_t* base = wimg + l * IMG_L;
    if (r == 60) {                       // rW pad image: 4 sub-stages [32f][32k]
        const float* W = msg_W + l * 35328 + 256 * 128;
        ushort_t* dst = base + IMG_RW;
        for (int e = 0; e < 16; ++e) {
            int q = threadIdx.x * 16 + e;
            int sub = q >> 10, n = (q >> 5) & 31, k = q & 31;
            dst[q] = f2bf(k < 20 ? W[(size_t)k * 128 + sub * 32 + n] : 0.0f);
        }
        return;
    }
    const float* W; int ld = 128, k0 = 0, c0, off, st;
    if      (r < 4)  { W = msg_W + l * 35328;            st = r;      off = IMG_WI;  c0 = st * 32; }
    else if (r < 8)  { W = msg_W + l * 35328;  k0 = 128; st = r - 4;  off = IMG_WJ;  c0 = st * 32; }
    else if (r < 12) { W = upd_W + l * 16384;            st = r - 8;  off = IMG_UW;  c0 = st * 32; }
    else if (r < 16) { W = gself_W + l * 16384;          st = r - 12; off = IMG_GS;  c0 = st * 32; }
    else if (r < 20) { W = fus_W + l * 32768;            st = r - 16; off = IMG_FT;  c0 = st * 32; }
    else if (r < 24) { W = fus_W + l * 32768;  k0 = 128; st = r - 20; off = IMG_FB;  c0 = st * 32; }
    else if (r < 40) { W = cb_W1 + l * 65536;  ld = 512; st = r - 24; off = IMG_C1;  c0 = st * 32; }
    else if (r < 56) { int j = (r - 40) >> 2; W = cb_W2 + l * 65536; k0 = j * 128;
                       st = r - 40; off = IMG_C2; c0 = ((r - 40) & 3) * 32; }
    else             { W = gmean_W + l * 16384;          st = r - 56; off = IMG_GMT; c0 = st * 32; }
    ushort_t* dst = base + off + st * 4096;
    for (int e = 0; e < 16; ++e) {
        int q = threadIdx.x * 16 + e;
        int n = q >> 7, k = q & 127;
        dst[q] = f2bf(W[(size_t)(k0 + k) * ld + c0 + n]);
    }
}

// ========== preamble 2: kNN per graph (1 wave), validated logic ============
extern "C" __global__ __launch_bounds__(64)
void knn_kernel(const float* __restrict__ positions, char* __restrict__ ws)
{
    const int b = blockIdx.x, lane = threadIdx.x;
    float px = positions[b * 192 + lane * 3 + 0];
    float py = positions[b * 192 + lane * 3 + 1];
    float pz = positions[b * 192 + lane * 3 + 2];
    float* kd = (float*)(ws + WS_WEIGHTS + (size_t)b * KNN_STRIDE);
    float* ke = kd + 1024;
    ushort_t* ki = (ushort_t*)(ke + 1024);
    for (int n = 0; n < 64; ++n) {
        float dx = __fsub_rn(__shfl(px, n), px);
        float dy = __fsub_rn(__shfl(py, n), py);
        float dz = __fsub_rn(__shfl(pz, n), pz);
        float d2 = __fadd_rn(__fadd_rn(__fmul_rn(dx, dx), __fmul_rn(dy, dy)), __fmul_rn(dz, dz));
        if (lane == n) d2 = 1e30f;
        float sd = 0.f; int si = 0;
        for (int k = 0; k < 16; ++k) {
            float dmin = d2;
            #pragma unroll
            for (int o = 1; o < 64; o <<= 1) dmin = fminf(dmin, __shfl_xor(dmin, o));
            ull_t mask = __ballot(d2 == dmin);
            int widx = __ffsll(mask) - 1;       // lowest index on ties (= top_k)
            if (lane == widx) d2 = 1e30f;
            if (lane == k) { si = widx; sd = dmin; }
        }
        if (lane < 16) {
            float dd = sqrtf(fmaxf(sd, 1e-12f));
            kd[n * 16 + lane] = dd;
            ke[n * 16 + lane] = (dd < 5.0f) ? 0.5f * (__cosf(0.62831853071795864769f * dd) + 1.0f) : 0.0f;
            ki[n * 16 + lane] = (ushort_t)si;
        }
    }
}

// ========== main fused kernel ==============================================
// 256 threads = 4 waves; wave w owns rows w*16..w*16+15 (ALL 128 cols).
// Residual h lives in registers (hreg[8][4], C-layout). LDS = 45056 B
// -> 3 blocks/CU (12 waves, 3/SIMD); __launch_bounds__(256,3) => ~170 VGPR cap.
struct __align__(16) Smem {
    ushort_t T1[N_ * H_];   // 16384B
    ushort_t T2[N_ * H_];   // 16384B
    float d[1024];          //  4096B
    float env[1024];        //  4096B
    ushort_t idx[1024];     //  2048B
    char u[2048];           // union: spos(768) | {part bf16 1024, hmean 512, gvec 512}
};

// one output stage s (16 cols, col = s*16+l15), K=128: 4 B-frags from global
__device__ __forceinline__ f32x4 gemm_s(const short8 a[4], const ushort_t* __restrict__ img,
                                        int s, int l15, int quad)
{
    const ushort_t* base = img + ((s >> 1) << 12) + ((((s & 1) << 4) + l15) << 7) + quad * 8;
    short8 b0 = *(const short8*)(base);
    short8 b1 = *(const short8*)(base + 32);
    short8 b2 = *(const short8*)(base + 64);
    short8 b3 = *(const short8*)(base + 96);
    f32x4 c = {0.f, 0.f, 0.f, 0.f};
    c = __builtin_amdgcn_mfma_f32_16x16x32_bf16(a[0], b0, c, 0, 0, 0);
    c = __builtin_amdgcn_mfma_f32_16x16x32_bf16(a[1], b1, c, 0, 0, 0);
    c = __builtin_amdgcn_mfma_f32_16x16x32_bf16(a[2], b2, c, 0, 0, 0);
    c = __builtin_amdgcn_mfma_f32_16x16x32_bf16(a[3], b3, c, 0, 0, 0);
    return c;
}
__device__ __forceinline__ f32x4 gemm_s_acc(const short8 a[4], const ushort_t* __restrict__ img,
                                            int s, int l15, int quad, f32x4 c)
{
    const ushort_t* base = img + ((s >> 1) << 12) + ((((s & 1) << 4) + l15) << 7) + quad * 8;
    short8 b0 = *(const short8*)(base);
    short8 b1 = *(const short8*)(base + 32);
    short8 b2 = *(const short8*)(base + 64);
    short8 b3 = *(const short8*)(base + 96);
    c = __builtin_amdgcn_mfma_f32_16x16x32_bf16(a[0], b0, c, 0, 0, 0);
    c = __builtin_amdgcn_mfma_f32_16x16x32_bf16(a[1], b1, c, 0, 0, 0);
    c = __builtin_amdgcn_mfma_f32_16x16x32_bf16(a[2], b2, c, 0, 0, 0);
    c = __builtin_amdgcn_mfma_f32_16x16x32_bf16(a[3], b3, c, 0, 0, 0);
    return c;
}
__device__ __forceinline__ void loadA(const ushort_t* __restrict__ X, int mrow, int quad, short8 a[4]) {
    #pragma unroll
    for (int kc = 0; kc < 4; ++kc) a[kc] = *(const short8*)&X[fragoff(mrow, kc * 4 + quad)];
}

extern "C" __global__ __launch_bounds__(NT, 3)
void md17_fused_kernel(
    const float* __restrict__ positions, const int* __restrict__ atomic_numbers,
    const float* __restrict__ atom_embed, const float* __restrict__ pos_W,
    const float* __restrict__ pos_b,
    const float* __restrict__ msg_b, const float* __restrict__ upd_b,
    const float* __restrict__ g_b, const float* __restrict__ fus_b,
    const float* __restrict__ ln_g, const float* __restrict__ ln_b,
    const float* __restrict__ cb_b1, const float* __restrict__ cb_b2,
    const float* __restrict__ fo_b1,
    const float* __restrict__ fo_W2, const float* __restrict__ fo_b2,
    char* __restrict__ ws, float* __restrict__ out)
{
    __shared__ Smem sm;
    const int b = blockIdx.x;
    const int tid = threadIdx.x;
    const int wave = tid >> 6, lane = tid & 63;
    const int quad = lane >> 4, l15 = lane & 15;
    const int mrow = wave * 16 + l15;       // A-frag row (wave-owned)
    const int rbase = wave * 16 + quad * 4; // C-tile row base (wave-owned)

    const ushort_t* wimg = (const ushort_t*)ws;
    float* spos = (float*)sm.u;
    ushort_t* part = (ushort_t*)sm.u;       // [4][128] bf16 hmean partials
    float* hmean = (float*)(sm.u + 1024);
    float* gvec  = (float*)(sm.u + 1536);

    // ---- setup: kNN blob + positions ----
    {
        const char* kb = ws + WS_WEIGHTS + (size_t)b * KNN_STRIDE;
        const float* kd = (const float*)kb;
        const float* ke = (const float*)(kb + 4096);
        const uint_t* ki = (const uint_t*)(kb + 8192);
        for (int t = tid; t < 1024; t += NT) { sm.d[t] = kd[t]; sm.env[t] = ke[t]; }
        for (int t = tid; t < 512; t += NT) ((uint_t*)sm.idx)[t] = ki[t];
        if (tid < 192) spos[tid] = positions[b * 192 + tid];
    }
    __syncthreads();

    // ---- embeddings -> hreg (register residual, C-layout) + T1 (bf16 image) ----
    float hreg[8][4];
    {
        int types[4];
        #pragma unroll
        for (int r = 0; r < 4; ++r) types[r] = atomic_numbers[b * N_ + rbase + r];
        #pragma unroll
        for (int s = 0; s < 8; ++s) {
            int col = s * 16 + l15;
            #pragma unroll
            for (int r = 0; r < 4; ++r) {
                int row = rbase + r;
                float v;
                if (col < 32) v = atom_embed[types[r] * 32 + col];
                else {
                    int j = col - 32;
                    v = pos_b[j];
                    #pragma unroll
                    for (int c = 0; c < 3; ++c)
                        v = fmaf(spos[row * 3 + c], pos_W[c * 96 + j], v);
                }
                hreg[s][r] = v;
                sm.T1[sidx(row, col)] = f2bf(v);
            }
        }
    }

    #pragma unroll 1
    for (int l = 0; l < 4; ++l) {
        const ushort_t* wl = wimg + l * IMG_L;
        const float* mb  = msg_b + l * H_;
        const float* ub  = upd_b + l * H_;
        const float* gb  = g_b + l * H_;
        const float* fb  = fus_b + l * H_;
        const float* lg  = ln_g + l * H_;
        const float* lb  = ln_b + l * H_;
        const float* c1b = cb_b1 + l * 4 * H_;
        const float* c2b = cb_b2 + l * H_;

        // A: hmean partials from hreg (registers)
        #pragma unroll
        for (int s = 0; s < 8; ++s) {
            float p = hreg[s][0] + hreg[s][1] + hreg[s][2] + hreg[s][3];
            p += __shfl_xor(p, 16);
            p += __shfl_xor(p, 32);
            if (quad == 0) part[wave * 128 + s * 16 + l15] = f2bf(p);
        }
        __syncthreads();                                 // B1
        if (tid < H_)
            hmean[tid] = (bf2f(part[tid]) + bf2f(part[128 + tid])
                        + bf2f(part[256 + tid]) + bf2f(part[384 + tid])) * (1.0f / 64.0f);
        __syncthreads();                                 // B2

        // C: gvec GEMV (waves 0-1) ; a_h ; WI -> T1 (+mb) ; WJ -> T2
        short8 a_h[4]; loadA(sm.T1, mrow, quad, a_h);    // h image, own rows
        if (tid < H_) {
            float s = gb[tid];
            const ushort_t* wrow = wl + IMG_GMT + tid * 128;
            for (int c = 0; c < 128; c += 8) {
                short8 w = *(const short8*)(wrow + c);
                #pragma unroll
                for (int i = 0; i < 8; ++i) s = fmaf(hmean[c + i], bf2f((ushort_t)w[i]), s);
            }
            gvec[tid] = s;
        }
        #pragma unroll
        for (int s = 0; s < 8; ++s) {
            f32x4 c = gemm_s(a_h, wl + IMG_WI, s, l15, quad);
            int col = s * 16 + l15; float bv = mb[col];
            #pragma unroll
            for (int r = 0; r < 4; ++r)
                sm.T1[sidx(rbase + r, col)] = f2bf(c[r] + bv);
        }
        #pragma unroll
        for (int s = 0; s < 8; ++s) {
            f32x4 c = gemm_s(a_h, wl + IMG_WJ, s, l15, quad);
            int col = s * 16 + l15;
            #pragma unroll
            for (int r = 0; r < 4; ++r)
                sm.T2[sidx(rbase + r, col)] = f2bf(c[r]);
        }
        __syncthreads();                                 // B3 (Gm visible to all)

        // D: msum — whole wave per atom n = wave*16+g (own rows), in place in T1
        {
            float ccv[8];
            #pragma unroll
            for (int j = 0; j < 8; ++j)
                ccv[j] = (float)((double)(quad * 8 + j) * (5.0 / 19.0));
            #pragma unroll 1
            for (int g = 0; g < 16; ++g) {
                int n = wave * 16 + g;
                int jv[4]; float ev[4];
                #pragma unroll
                for (int r = 0; r < 4; ++r) {
                    int k = quad * 4 + r;
                    jv[r] = sm.idx[n * 16 + k];
                    ev[r] = sm.env[n * 16 + k];
                }
                float ddm = sm.d[n * 16 + l15];
                short8 arb;
                #pragma unroll
                for (int j = 0; j < 8; ++j) {
                    float t2 = ddm - ccv[j];
                    float rv = __expf(-10.0f * t2 * t2);
                    arb[j] = (short)((quad * 8 + j) < 20 ? f2bf(rv) : (ushort_t)0);
                }
                #pragma unroll
                for (int s = 0; s < 8; ++s) {
                    int col = s * 16 + l15;
                    const ushort_t* rp = wl + IMG_RW + ((s >> 1) << 10)
                                       + ((((s & 1) << 4) + l15) << 5) + quad * 8;
                    short8 brw = *(const short8*)rp;
                    f32x4 c = {0.f, 0.f, 0.f, 0.f};
                    c = __builtin_amdgcn_mfma_f32_16x16x32_bf16(arb, brw, c, 0, 0, 0);
                    float ai = bf2f(sm.T1[sidx(n, col)]);
                    float acc = 0.f;
                    #pragma unroll
                    for (int r = 0; r < 4; ++r) {
                        float gm = bf2f(sm.T2[sidx(jv[r], col)]);
                        acc = fmaf(siluf(ai + gm + c[r]), ev[r], acc);
                    }
                    acc += __shfl_xor(acc, 16);
                    acc += __shfl_xor(acc, 32);
                    if (quad == 0) sm.T1[sidx(n, col)] = f2bf(acc);
                }
            }
        }
        __syncthreads();                                 // B4 (gather done; T2 free)

        // ---- free-run region: only own rows below ----

        // F: UW(a_m)+hreg -> T2 local ; GS(a_h)+gvec -> T1 glob
        short8 a_loc[4], a_gl[4];
        {
            short8 a_m[4]; loadA(sm.T1, mrow, quad, a_m);
            #pragma unroll
            for (int s = 0; s < 8; ++s) {
                f32x4 c = gemm_s(a_m, wl + IMG_UW, s, l15, quad);
                int col = s * 16 + l15; float bv = ub[col];
                #pragma unroll
                for (int r = 0; r < 4; ++r)
                    sm.T2[sidx(rbase + r, col)] = f2bf(hreg[s][r] + siluf(c[r] + bv));
            }
            loadA(sm.T2, mrow, quad, a_loc);
            #pragma unroll
            for (int s = 0; s < 8; ++s) {
                f32x4 c = gemm_s(a_h, wl + IMG_GS, s, l15, quad);
                int col = s * 16 + l15; float gv = gvec[col];
                #pragma unroll
                for (int r = 0; r < 4; ++r)
                    sm.T1[sidx(rbase + r, col)] = f2bf(siluf(c[r] + gv));
            }
            loadA(sm.T1, mrow, quad, a_gl);
        }

        // G: fused = silu(local@FT + glob@FB + fb) -> hreg ; LN sums in regs
        float sr[4] = {0.f, 0.f, 0.f, 0.f}, qr[4] = {0.f, 0.f, 0.f, 0.f};
        #pragma unroll
        for (int s = 0; s < 8; ++s) {
            f32x4 c = gemm_s(a_loc, wl + IMG_FT, s, l15, quad);
            c = gemm_s_acc(a_gl, wl + IMG_FB, s, l15, quad, c);
            int col = s * 16 + l15; float bv = fb[col];
            #pragma unroll
            for (int r = 0; r < 4; ++r) {
                float v = siluf(c[r] + bv);
                hreg[s][r] = v;
                sr[r] += v; qr[r] += v * v;
            }
        }
        #pragma unroll
        for (int o = 1; o < 16; o <<= 1) {
            #pragma unroll
            for (int r = 0; r < 4; ++r) {
                sr[r] += __shfl_xor(sr[r], o);
                qr[r] += __shfl_xor(qr[r], o);
            }
        }

        // H: LN normalize (wave-local, from hreg) -> T1 (x-hat)
        #pragma unroll
        for (int r = 0; r < 4; ++r) {
            float mu = sr[r] * (1.0f / 128.0f);
            float var = qr[r] * (1.0f / 128.0f) - mu * mu;
            float rs = rsqrtf(var + 1e-5f);
            int row = rbase + r;
            #pragma unroll
            for (int s = 0; s < 8; ++s) {
                int col = s * 16 + l15;
                sm.T1[sidx(row, col)] = f2bf((hreg[s][r] - mu) * rs * lg[col] + lb[col]);
            }
        }

        // J: Clifford MLP, 4 K-chunks; C1 -> T2; C2 -> register acc2 (no barriers)
        {
            short8 a_x[4]; loadA(sm.T1, mrow, quad, a_x);
            f32x4 acc2[8];
            #pragma unroll
            for (int s = 0; s < 8; ++s) acc2[s] = (f32x4){0.f, 0.f, 0.f, 0.f};
            #pragma unroll 1
            for (int j = 0; j < 4; ++j) {
                #pragma unroll
                for (int s = 0; s < 8; ++s) {
                    f32x4 c = gemm_s(a_x, wl + IMG_C1 + j * 16384, s, l15, quad);
                    int col = s * 16 + l15; float bv = c1b[j * H_ + col];
                    #pragma unroll
                    for (int r = 0; r < 4; ++r)
                        sm.T2[sidx(rbase + r, col)] = f2bf(siluf(c[r] + bv));
                }
                short8 a_t[4]; loadA(sm.T2, mrow, quad, a_t);
                #pragma unroll
                for (int s = 0; s < 8; ++s)
                    acc2[s] = gemm_s_acc(a_t, wl + IMG_C2 + j * 16384, s, l15, quad, acc2[s]);
            }
            // K: h_next = fused(hreg) + acc2 + c2b -> hreg + T1 image
            #pragma unroll
            for (int s = 0; s < 8; ++s) {
                int col = s * 16 + l15; float bv = c2b[col];
                #pragma unroll
                for (int r = 0; r < 4; ++r) {
                    float v = hreg[s][r] + acc2[s][r] + bv;
                    hreg[s][r] = v;
                    sm.T1[sidx(rbase + r, col)] = f2bf(v);
                }
            }
        }
        // no layer-end barrier: next stage A reads hreg; a_h load is own-rows
    }

    // ---- head: FO -> T2 (own rows) ; barrier ; gather -> out ----
    {
        short8 a_f[4]; loadA(sm.T1, mrow, quad, a_f);
        #pragma unroll
        for (int s = 0; s < 8; ++s) {
            f32x4 c = gemm_s(a_f, wimg + IMG_FO, s, l15, quad);
            int col = s * 16 + l15; float bv = fo_b1[col];
            #pragma unroll
            for (int r = 0; r < 4; ++r)
                sm.T2[sidx(rbase + r, col)] = f2bf(siluf(c[r] + bv));
        }
    }
    __syncthreads();
    if (tid < 192) {
        int n = tid / 3, j = tid - n * 3;
        float s = fo_b2[j];
        for (int c = 0; c < H_; ++c)
            s = fmaf(bf2f(sm.T2[sidx(n, c)]), fo_W2[c * 3 + j], s);
        out[b * 192 + tid] = s;
    }
}

extern "C" void kernel_launch(void* const* d_in, const int* in_sizes, int n_in,
                              void* d_out, int out_size, void* d_ws, size_t ws_size,
                              hipStream_t stream) {
    (void)in_sizes; (void)n_in; (void)out_size; (void)ws_size;
    convert_weights<<<248, 256, 0, stream>>>(
        (const float*)d_in[5], (const float*)d_in[7], (const float*)d_in[9],
        (const float*)d_in[12], (const float*)d_in[16], (const float*)d_in[18],
        (const float*)d_in[10], (const float*)d_in[20], (ushort_t*)d_ws);
    knn_kernel<<<B_, 64, 0, stream>>>((const float*)d_in[0], (char*)d_ws);
    md17_fused_kernel<<<B_, NT, 0, stream>>>(
        (const float*)d_in[0], (const int*)d_in[1],
        (const float*)d_in[2], (const float*)d_in[3], (const float*)d_in[4],
        (const float*)d_in[6], (const float*)d_in[8],
        (const float*)d_in[11], (const float*)d_in[13],
        (const float*)d_in[14], (const float*)d_in[15],
        (const float*)d_in[17], (const float*)d_in[19],
        (const float*)d_in[21],
        (const float*)d_in[22], (const float*)d_in[23],
        (char*)d_ws, (float*)d_out);
}

// Round 13
// 1557.657 us; speedup vs baseline: 1.1086x; 1.1086x over previous
//
#include <hip/hip_runtime.h>

typedef unsigned short ushort_t;
typedef unsigned int uint_t;
typedef unsigned long long ull_t;
typedef __attribute__((ext_vector_type(8))) short short8;
typedef __attribute__((ext_vector_type(4))) float f32x4;

#define B_ 1024
#define N_ 64
#define H_ 128
#define NT 256

// bf16 weight-image element offsets
#define IMG_WI 0
#define IMG_WJ 16384
#define IMG_UW 32768
#define IMG_GS 49152
#define IMG_FT 65536
#define IMG_FB 81920
#define IMG_C1 98304
#define IMG_C2 163840
#define IMG_GMT 229376
#define IMG_RW 245760
#define IMG_L 249856
#define IMG_FO 999424
#define WS_WEIGHTS (2u*1024u*1024u)
#define KNN_STRIDE 12288u

__device__ __forceinline__ ushort_t f2bf(float f) {
    uint_t u = __float_as_uint(f);
    return (ushort_t)((u + 0x7fffu + ((u >> 16) & 1u)) >> 16);
}
__device__ __forceinline__ float bf2f(ushort_t u) {
    union { uint_t i; float f; } v; v.i = ((uint_t)u) << 16; return v.f;
}
__device__ __forceinline__ float siluf(float x) { return x / (1.0f + __expf(-x)); }

// LDS swizzle: 16B-chunk c of row m stored at chunk c ^ (m&7)
__device__ __forceinline__ int sidx(int m, int k) {
    return m * H_ + (((k >> 3) ^ (m & 7)) << 3) + (k & 7);
}
__device__ __forceinline__ int fragoff(int m, int ch) {
    return m * H_ + ((ch ^ (m & 7)) << 3);
}

// ========== preamble 1: f32 weights -> transposed bf16 images ==============
extern "C" __global__ __launch_bounds__(256)
void convert_weights(const float* __restrict__ msg_W, const float* __restrict__ upd_W,
                     const float* __restrict__ gself_W, const float* __restrict__ fus_W,
                     const float* __restrict__ cb_W1, const float* __restrict__ cb_W2,
                     const float* __restrict__ gmean_W, const float* __restrict__ fo_W1,
                     ushort_t* __restrict__ wimg)
{
    const int g = blockIdx.x;
    if (g >= 244) {
        int st = g - 244;
        ushort_t* dst = wimg + IMG_FO + st * 4096;
        for (int e = 0; e < 16; ++e) {
            int q = threadIdx.x * 16 + e;
            int n = q >> 7, k = q & 127;
            dst[q] = f2bf(fo_W1[(size_t)k * 128 + st * 32 + n]);
        }
        return;
    }
    const int l = g / 61, r = g - l * 61;
    ushort_t* base = wimg + l * IMG_L;
    if (r == 60) {                       // rW pad image: 4 sub-stages [32f][32k]
        const float* W = msg_W + l * 35328 + 256 * 128;
        ushort_t* dst = base + IMG_RW;
        for (int e = 0; e < 16; ++e) {
            int q = threadIdx.x * 16 + e;
            int sub = q >> 10, n = (q >> 5) & 31, k = q & 31;
            dst[q] = f2bf(k < 20 ? W[(size_t)k * 128 + sub * 32 + n] : 0.0f);
        }
        return;
    }
    const float* W; int ld = 128, k0 = 0, c0, off, st;
    if      (r < 4)  { W = msg_W + l * 35328;            st = r;      off = IMG_WI;  c0 = st * 32; }
    else if (r < 8)  { W = msg_W + l * 35328;  k0 = 128; st = r - 4;  off = IMG_WJ;  c0 = st * 32; }
    else if (r < 12) { W = upd_W + l * 16384;            st = r - 8;  off = IMG_UW;  c0 = st * 32; }
    else if (r < 16) { W = gself_W + l * 16384;          st = r - 12; off = IMG_GS;  c0 = st * 32; }
    else if (r < 20) { W = fus_W + l * 32768;            st = r - 16; off = IMG_FT;  c0 = st * 32; }
    else if (r < 24) { W = fus_W + l * 32768;  k0 = 128; st = r - 20; off = IMG_FB;  c0 = st * 32; }
    else if (r < 40) { W = cb_W1 + l * 65536;  ld = 512; st = r - 24; off = IMG_C1;  c0 = st * 32; }
    else if (r < 56) { int j = (r - 40) >> 2; W = cb_W2 + l * 65536; k0 = j * 128;
                       st = r - 40; off = IMG_C2; c0 = ((r - 40) & 3) * 32; }
    else             { W = gmean_W + l * 16384;          st = r - 56; off = IMG_GMT; c0 = st * 32; }
    ushort_t* dst = base + off + st * 4096;
    for (int e = 0; e < 16; ++e) {
        int q = threadIdx.x * 16 + e;
        int n = q >> 7, k = q & 127;
        dst[q] = f2bf(W[(size_t)(k0 + k) * ld + c0 + n]);
    }
}

// ========== preamble 2: kNN per graph (1 wave), validated logic ============
extern "C" __global__ __launch_bounds__(64)
void knn_kernel(const float* __restrict__ positions, char* __restrict__ ws)
{
    const int b = blockIdx.x, lane = threadIdx.x;
    float px = positions[b * 192 + lane * 3 + 0];
    float py = positions[b * 192 + lane * 3 + 1];
    float pz = positions[b * 192 + lane * 3 + 2];
    float* kd = (float*)(ws + WS_WEIGHTS + (size_t)b * KNN_STRIDE);
    float* ke = kd + 1024;
    ushort_t* ki = (ushort_t*)(ke + 1024);
    for (int n = 0; n < 64; ++n) {
        float dx = __fsub_rn(__shfl(px, n), px);
        float dy = __fsub_rn(__shfl(py, n), py);
        float dz = __fsub_rn(__shfl(pz, n), pz);
        float d2 = __fadd_rn(__fadd_rn(__fmul_rn(dx, dx), __fmul_rn(dy, dy)), __fmul_rn(dz, dz));
        if (lane == n) d2 = 1e30f;
        float sd = 0.f; int si = 0;
        for (int k = 0; k < 16; ++k) {
            float dmin = d2;
            #pragma unroll
            for (int o = 1; o < 64; o <<= 1) dmin = fminf(dmin, __shfl_xor(dmin, o));
            ull_t mask = __ballot(d2 == dmin);
            int widx = __ffsll(mask) - 1;       // lowest index on ties (= top_k)
            if (lane == widx) d2 = 1e30f;
            if (lane == k) { si = widx; sd = dmin; }
        }
        if (lane < 16) {
            float dd = sqrtf(fmaxf(sd, 1e-12f));
            kd[n * 16 + lane] = dd;
            ke[n * 16 + lane] = (dd < 5.0f) ? 0.5f * (__cosf(0.62831853071795864769f * dd) + 1.0f) : 0.0f;
            ki[n * 16 + lane] = (ushort_t)si;
        }
    }
}

// ========== main fused kernel ==============================================
// 256 threads = 4 waves; wave w owns rows w*16..w*16+15 (ALL 128 cols).
// Residual h lives in registers (hreg[8][4], C-layout). LDS = 45056 B
// -> 3 blocks/CU (12 waves, 3/SIMD). launch_bounds(256,2): loose VGPR cap
// (256) so the compiler allocates what the design needs (~150) with NO
// spills — r12's (256,3) made it target 84 VGPR and spill (FETCH/WRITE
// exploded). LDS already caps occupancy at 3 waves/SIMD.
struct __align__(16) Smem {
    ushort_t T1[N_ * H_];   // 16384B
    ushort_t T2[N_ * H_];   // 16384B
    float d[1024];          //  4096B
    float env[1024];        //  4096B
    ushort_t idx[1024];     //  2048B
    char u[2048];           // union: spos(768) | {part bf16 1024, hmean 512, gvec 512}
};

// one output stage s (16 cols, col = s*16+l15), K=128: 4 B-frags from global
__device__ __forceinline__ f32x4 gemm_s(const short8 a[4], const ushort_t* __restrict__ img,
                                        int s, int l15, int quad)
{
    const ushort_t* base = img + ((s >> 1) << 12) + ((((s & 1) << 4) + l15) << 7) + quad * 8;
    short8 b0 = *(const short8*)(base);
    short8 b1 = *(const short8*)(base + 32);
    short8 b2 = *(const short8*)(base + 64);
    short8 b3 = *(const short8*)(base + 96);
    f32x4 c = {0.f, 0.f, 0.f, 0.f};
    c = __builtin_amdgcn_mfma_f32_16x16x32_bf16(a[0], b0, c, 0, 0, 0);
    c = __builtin_amdgcn_mfma_f32_16x16x32_bf16(a[1], b1, c, 0, 0, 0);
    c = __builtin_amdgcn_mfma_f32_16x16x32_bf16(a[2], b2, c, 0, 0, 0);
    c = __builtin_amdgcn_mfma_f32_16x16x32_bf16(a[3], b3, c, 0, 0, 0);
    return c;
}
__device__ __forceinline__ f32x4 gemm_s_acc(const short8 a[4], const ushort_t* __restrict__ img,
                                            int s, int l15, int quad, f32x4 c)
{
    const ushort_t* base = img + ((s >> 1) << 12) + ((((s & 1) << 4) + l15) << 7) + quad * 8;
    short8 b0 = *(const short8*)(base);
    short8 b1 = *(const short8*)(base + 32);
    short8 b2 = *(const short8*)(base + 64);
    short8 b3 = *(const short8*)(base + 96);
    c = __builtin_amdgcn_mfma_f32_16x16x32_bf16(a[0], b0, c, 0, 0, 0);
    c = __builtin_amdgcn_mfma_f32_16x16x32_bf16(a[1], b1, c, 0, 0, 0);
    c = __builtin_amdgcn_mfma_f32_16x16x32_bf16(a[2], b2, c, 0, 0, 0);
    c = __builtin_amdgcn_mfma_f32_16x16x32_bf16(a[3], b3, c, 0, 0, 0);
    return c;
}
__device__ __forceinline__ void loadA(const ushort_t* __restrict__ X, int mrow, int quad, short8 a[4]) {
    #pragma unroll
    for (int kc = 0; kc < 4; ++kc) a[kc] = *(const short8*)&X[fragoff(mrow, kc * 4 + quad)];
}

extern "C" __global__ __launch_bounds__(NT, 2)
void md17_fused_kernel(
    const float* __restrict__ positions, const int* __restrict__ atomic_numbers,
    const float* __restrict__ atom_embed, const float* __restrict__ pos_W,
    const float* __restrict__ pos_b,
    const float* __restrict__ msg_b, const float* __restrict__ upd_b,
    const float* __restrict__ g_b, const float* __restrict__ fus_b,
    const float* __restrict__ ln_g, const float* __restrict__ ln_b,
    const float* __restrict__ cb_b1, const float* __restrict__ cb_b2,
    const float* __restrict__ fo_b1,
    const float* __restrict__ fo_W2, const float* __restrict__ fo_b2,
    char* __restrict__ ws, float* __restrict__ out)
{
    __shared__ Smem sm;
    const int b = blockIdx.x;
    const int tid = threadIdx.x;
    const int wave = tid >> 6, lane = tid & 63;
    const int quad = lane >> 4, l15 = lane & 15;
    const int mrow = wave * 16 + l15;       // A-frag row (wave-owned)
    const int rbase = wave * 16 + quad * 4; // C-tile row base (wave-owned)

    const ushort_t* wimg = (const ushort_t*)ws;
    float* spos = (float*)sm.u;
    ushort_t* part = (ushort_t*)sm.u;       // [4][128] bf16 hmean partials
    float* hmean = (float*)(sm.u + 1024);
    float* gvec  = (float*)(sm.u + 1536);

    // ---- setup: kNN blob + positions ----
    {
        const char* kb = ws + WS_WEIGHTS + (size_t)b * KNN_STRIDE;
        const float* kd = (const float*)kb;
        const float* ke = (const float*)(kb + 4096);
        const uint_t* ki = (const uint_t*)(kb + 8192);
        for (int t = tid; t < 1024; t += NT) { sm.d[t] = kd[t]; sm.env[t] = ke[t]; }
        for (int t = tid; t < 512; t += NT) ((uint_t*)sm.idx)[t] = ki[t];
        if (tid < 192) spos[tid] = positions[b * 192 + tid];
    }
    __syncthreads();

    // ---- embeddings -> hreg (register residual, C-layout) + T1 (bf16 image) ----
    float hreg[8][4];
    {
        int types[4];
        #pragma unroll
        for (int r = 0; r < 4; ++r) types[r] = atomic_numbers[b * N_ + rbase + r];
        #pragma unroll
        for (int s = 0; s < 8; ++s) {
            int col = s * 16 + l15;
            #pragma unroll
            for (int r = 0; r < 4; ++r) {
                int row = rbase + r;
                float v;
                if (col < 32) v = atom_embed[types[r] * 32 + col];
                else {
                    int j = col - 32;
                    v = pos_b[j];
                    #pragma unroll
                    for (int c = 0; c < 3; ++c)
                        v = fmaf(spos[row * 3 + c], pos_W[c * 96 + j], v);
                }
                hreg[s][r] = v;
                sm.T1[sidx(row, col)] = f2bf(v);
            }
        }
    }

    #pragma unroll 1
    for (int l = 0; l < 4; ++l) {
        const ushort_t* wl = wimg + l * IMG_L;
        const float* mb  = msg_b + l * H_;
        const float* ub  = upd_b + l * H_;
        const float* gb  = g_b + l * H_;
        const float* fb  = fus_b + l * H_;
        const float* lg  = ln_g + l * H_;
        const float* lb  = ln_b + l * H_;
        const float* c1b = cb_b1 + l * 4 * H_;
        const float* c2b = cb_b2 + l * H_;

        // A: hmean partials from hreg (registers)
        #pragma unroll
        for (int s = 0; s < 8; ++s) {
            float p = hreg[s][0] + hreg[s][1] + hreg[s][2] + hreg[s][3];
            p += __shfl_xor(p, 16);
            p += __shfl_xor(p, 32);
            if (quad == 0) part[wave * 128 + s * 16 + l15] = f2bf(p);
        }
        __syncthreads();                                 // B1
        if (tid < H_)
            hmean[tid] = (bf2f(part[tid]) + bf2f(part[128 + tid])
                        + bf2f(part[256 + tid]) + bf2f(part[384 + tid])) * (1.0f / 64.0f);
        __syncthreads();                                 // B2

        // C: gvec GEMV (waves 0-1) ; a_h ; WI -> T1 (+mb) ; WJ -> T2
        short8 a_h[4]; loadA(sm.T1, mrow, quad, a_h);    // h image, own rows
        if (tid < H_) {
            float s = gb[tid];
            const ushort_t* wrow = wl + IMG_GMT + tid * 128;
            for (int c = 0; c < 128; c += 8) {
                short8 w = *(const short8*)(wrow + c);
                #pragma unroll
                for (int i = 0; i < 8; ++i) s = fmaf(hmean[c + i], bf2f((ushort_t)w[i]), s);
            }
            gvec[tid] = s;
        }
        #pragma unroll
        for (int s = 0; s < 8; ++s) {
            f32x4 c = gemm_s(a_h, wl + IMG_WI, s, l15, quad);
            int col = s * 16 + l15; float bv = mb[col];
            #pragma unroll
            for (int r = 0; r < 4; ++r)
                sm.T1[sidx(rbase + r, col)] = f2bf(c[r] + bv);
        }
        #pragma unroll
        for (int s = 0; s < 8; ++s) {
            f32x4 c = gemm_s(a_h, wl + IMG_WJ, s, l15, quad);
            int col = s * 16 + l15;
            #pragma unroll
            for (int r = 0; r < 4; ++r)
                sm.T2[sidx(rbase + r, col)] = f2bf(c[r]);
        }
        __syncthreads();                                 // B3 (Gm visible to all)

        // D: msum — whole wave per atom n = wave*16+g (own rows), in place in T1
        {
            float ccv[8];
            #pragma unroll
            for (int j = 0; j < 8; ++j)
                ccv[j] = (float)((double)(quad * 8 + j) * (5.0 / 19.0));
            #pragma unroll 1
            for (int g = 0; g < 16; ++g) {
                int n = wave * 16 + g;
                int jv[4]; float ev[4];
                #pragma unroll
                for (int r = 0; r < 4; ++r) {
                    int k = quad * 4 + r;
                    jv[r] = sm.idx[n * 16 + k];
                    ev[r] = sm.env[n * 16 + k];
                }
                float ddm = sm.d[n * 16 + l15];
                short8 arb;
                #pragma unroll
                for (int j = 0; j < 8; ++j) {
                    float t2 = ddm - ccv[j];
                    float rv = __expf(-10.0f * t2 * t2);
                    arb[j] = (short)((quad * 8 + j) < 20 ? f2bf(rv) : (ushort_t)0);
                }
                #pragma unroll
                for (int s = 0; s < 8; ++s) {
                    int col = s * 16 + l15;
                    const ushort_t* rp = wl + IMG_RW + ((s >> 1) << 10)
                                       + ((((s & 1) << 4) + l15) << 5) + quad * 8;
                    short8 brw = *(const short8*)rp;
                    f32x4 c = {0.f, 0.f, 0.f, 0.f};
                    c = __builtin_amdgcn_mfma_f32_16x16x32_bf16(arb, brw, c, 0, 0, 0);
                    float ai = bf2f(sm.T1[sidx(n, col)]);
                    float acc = 0.f;
                    #pragma unroll
                    for (int r = 0; r < 4; ++r) {
                        float gm = bf2f(sm.T2[sidx(jv[r], col)]);
                        acc = fmaf(siluf(ai + gm + c[r]), ev[r], acc);
                    }
                    acc += __shfl_xor(acc, 16);
                    acc += __shfl_xor(acc, 32);
                    if (quad == 0) sm.T1[sidx(n, col)] = f2bf(acc);
                }
            }
        }
        __syncthreads();                                 // B4 (gather done; T2 free)

        // ---- free-run region: only own rows below ----

        // F: UW(a_m)+hreg -> T2 local ; GS(a_h)+gvec -> T1 glob
        short8 a_loc[4], a_gl[4];
        {
            short8 a_m[4]; loadA(sm.T1, mrow, quad, a_m);
            #pragma unroll
            for (int s = 0; s < 8; ++s) {
                f32x4 c = gemm_s(a_m, wl + IMG_UW, s, l15, quad);
                int col = s * 16 + l15; float bv = ub[col];
                #pragma unroll
                for (int r = 0; r < 4; ++r)
                    sm.T2[sidx(rbase + r, col)] = f2bf(hreg[s][r] + siluf(c[r] + bv));
            }
            loadA(sm.T2, mrow, quad, a_loc);
            #pragma unroll
            for (int s = 0; s < 8; ++s) {
                f32x4 c = gemm_s(a_h, wl + IMG_GS, s, l15, quad);
                int col = s * 16 + l15; float gv = gvec[col];
                #pragma unroll
                for (int r = 0; r < 4; ++r)
                    sm.T1[sidx(rbase + r, col)] = f2bf(siluf(c[r] + gv));
            }
            loadA(sm.T1, mrow, quad, a_gl);
        }

        // G: fused = silu(local@FT + glob@FB + fb) -> hreg ; LN sums in regs
        float sr[4] = {0.f, 0.f, 0.f, 0.f}, qr[4] = {0.f, 0.f, 0.f, 0.f};
        #pragma unroll
        for (int s = 0; s < 8; ++s) {
            f32x4 c = gemm_s(a_loc, wl + IMG_FT, s, l15, quad);
            c = gemm_s_acc(a_gl, wl + IMG_FB, s, l15, quad, c);
            int col = s * 16 + l15; float bv = fb[col];
            #pragma unroll
            for (int r = 0; r < 4; ++r) {
                float v = siluf(c[r] + bv);
                hreg[s][r] = v;
                sr[r] += v; qr[r] += v * v;
            }
        }
        #pragma unroll
        for (int o = 1; o < 16; o <<= 1) {
            #pragma unroll
            for (int r = 0; r < 4; ++r) {
                sr[r] += __shfl_xor(sr[r], o);
                qr[r] += __shfl_xor(qr[r], o);
            }
        }

        // H: LN normalize (wave-local, from hreg) -> T1 (x-hat)
        #pragma unroll
        for (int r = 0; r < 4; ++r) {
            float mu = sr[r] * (1.0f / 128.0f);
            float var = qr[r] * (1.0f / 128.0f) - mu * mu;
            float rs = rsqrtf(var + 1e-5f);
            int row = rbase + r;
            #pragma unroll
            for (int s = 0; s < 8; ++s) {
                int col = s * 16 + l15;
                sm.T1[sidx(row, col)] = f2bf((hreg[s][r] - mu) * rs * lg[col] + lb[col]);
            }
        }

        // J: Clifford MLP, 4 K-chunks; C1 -> T2; C2 -> register acc2 (no barriers)
        {
            short8 a_x[4]; loadA(sm.T1, mrow, quad, a_x);
            f32x4 acc2[8];
            #pragma unroll
            for (int s = 0; s < 8; ++s) acc2[s] = (f32x4){0.f, 0.f, 0.f, 0.f};
            #pragma unroll 1
            for (int j = 0; j < 4; ++j) {
                #pragma unroll
                for (int s = 0; s < 8; ++s) {
                    f32x4 c = gemm_s(a_x, wl + IMG_C1 + j * 16384, s, l15, quad);
                    int col = s * 16 + l15; float bv = c1b[j * H_ + col];
                    #pragma unroll
                    for (int r = 0; r < 4; ++r)
                        sm.T2[sidx(rbase + r, col)] = f2bf(siluf(c[r] + bv));
                }
                short8 a_t[4]; loadA(sm.T2, mrow, quad, a_t);
                #pragma unroll
                for (int s = 0; s < 8; ++s)
                    acc2[s] = gemm_s_acc(a_t, wl + IMG_C2 + j * 16384, s, l15, quad, acc2[s]);
            }
            // K: h_next = fused(hreg) + acc2 + c2b -> hreg + T1 image
            #pragma unroll
            for (int s = 0; s < 8; ++s) {
                int col = s * 16 + l15; float bv = c2b[col];
                #pragma unroll
                for (int r = 0; r < 4; ++r) {
                    float v = hreg[s][r] + acc2[s][r] + bv;
                    hreg[s][r] = v;
                    sm.T1[sidx(rbase + r, col)] = f2bf(v);
                }
            }
        }
        // no layer-end barrier: next stage A reads hreg; a_h load is own-rows
    }

    // ---- head: FO -> T2 (own rows) ; barrier ; gather -> out ----
    {
        short8 a_f[4]; loadA(sm.T1, mrow, quad, a_f);
        #pragma unroll
        for (int s = 0; s < 8; ++s) {
            f32x4 c = gemm_s(a_f, wimg + IMG_FO, s, l15, quad);
            int col = s * 16 + l15; float bv = fo_b1[col];
            #pragma unroll
            for (int r = 0; r < 4; ++r)
                sm.T2[sidx(rbase + r, col)] = f2bf(siluf(c[r] + bv));
        }
    }
    __syncthreads();
    if (tid < 192) {
        int n = tid / 3, j = tid - n * 3;
        float s = fo_b2[j];
        for (int c = 0; c < H_; ++c)
            s = fmaf(bf2f(sm.T2[sidx(n, c)]), fo_W2[c * 3 + j], s);
        out[b * 192 + tid] = s;
    }
}

extern "C" void kernel_launch(void* const* d_in, const int* in_sizes, int n_in,
                              void* d_out, int out_size, void* d_ws, size_t ws_size,
                              hipStream_t stream) {
    (void)in_sizes; (void)n_in; (void)out_size; (void)ws_size;
    convert_weights<<<248, 256, 0, stream>>>(
        (const float*)d_in[5], (const float*)d_in[7], (const float*)d_in[9],
        (const float*)d_in[12], (const float*)d_in[16], (const float*)d_in[18],
        (const float*)d_in[10], (const float*)d_in[20], (ushort_t*)d_ws);
    knn_kernel<<<B_, 64, 0, stream>>>((const float*)d_in[0], (char*)d_ws);
    md17_fused_kernel<<<B_, NT, 0, stream>>>(
        (const float*)d_in[0], (const int*)d_in[1],
        (const float*)d_in[2], (const float*)d_in[3], (const float*)d_in[4],
        (const float*)d_in[6], (const float*)d_in[8],
        (const float*)d_in[11], (const float*)d_in[13],
        (const float*)d_in[14], (const float*)d_in[15],
        (const float*)d_in[17], (const float*)d_in[19],
        (const float*)d_in[21],
        (const float*)d_in[22], (const float*)d_in[23],
        (char*)d_ws, (float*)d_out);
}

// Round 14
// 1554.180 us; speedup vs baseline: 1.1111x; 1.0022x over previous
//
#include <hip/hip_runtime.h>

typedef unsigned short ushort_t;
typedef unsigned int uint_t;
typedef unsigned long long ull_t;
typedef __attribute__((ext_vector_type(8))) short short8;
typedef __attribute__((ext_vector_type(4))) float f32x4;

#define B_ 1024
#define N_ 64
#define H_ 128
#define NT 256

// bf16 weight-image element offsets
#define IMG_WI 0
#define IMG_WJ 16384
#define IMG_UW 32768
#define IMG_GS 49152
#define IMG_FT 65536
#define IMG_FB 81920
#define IMG_C1 98304
#define IMG_C2 163840
#define IMG_GMT 229376
#define IMG_RW 245760
#define IMG_L 249856
#define IMG_FO 999424
#define WS_WEIGHTS (2u*1024u*1024u)
#define KNN_STRIDE 12288u

__device__ __forceinline__ ushort_t f2bf(float f) {
    uint_t u = __float_as_uint(f);
    return (ushort_t)((u + 0x7fffu + ((u >> 16) & 1u)) >> 16);
}
__device__ __forceinline__ float bf2f(ushort_t u) {
    union { uint_t i; float f; } v; v.i = ((uint_t)u) << 16; return v.f;
}
__device__ __forceinline__ float siluf(float x) { return x / (1.0f + __expf(-x)); }

// LDS swizzle: 16B-chunk c of row m stored at chunk c ^ (m&7)
__device__ __forceinline__ int sidx(int m, int k) {
    return m * H_ + (((k >> 3) ^ (m & 7)) << 3) + (k & 7);
}
__device__ __forceinline__ int fragoff(int m, int ch) {
    return m * H_ + ((ch ^ (m & 7)) << 3);
}

// ========== preamble 1: f32 weights -> transposed bf16 images ==============
extern "C" __global__ __launch_bounds__(256)
void convert_weights(const float* __restrict__ msg_W, const float* __restrict__ upd_W,
                     const float* __restrict__ gself_W, const float* __restrict__ fus_W,
                     const float* __restrict__ cb_W1, const float* __restrict__ cb_W2,
                     const float* __restrict__ gmean_W, const float* __restrict__ fo_W1,
                     ushort_t* __restrict__ wimg)
{
    const int g = blockIdx.x;
    if (g >= 244) {
        int st = g - 244;
        ushort_t* dst = wimg + IMG_FO + st * 4096;
        for (int e = 0; e < 16; ++e) {
            int q = threadIdx.x * 16 + e;
            int n = q >> 7, k = q & 127;
            dst[q] = f2bf(fo_W1[(size_t)k * 128 + st * 32 + n]);
        }
        return;
    }
    const int l = g / 61, r = g - l * 61;
    ushort_t* base = wimg + l * IMG_L;
    if (r == 60) {                       // rW pad image: 4 sub-stages [32f][32k]
        const float* W = msg_W + l * 35328 + 256 * 128;
        ushort_t* dst = base + IMG_RW;
        for (int e = 0; e < 16; ++e) {
            int q = threadIdx.x * 16 + e;
            int sub = q >> 10, n = (q >> 5) & 31, k = q & 31;
            dst[q] = f2bf(k < 20 ? W[(size_t)k * 128 + sub * 32 + n] : 0.0f);
        }
        return;
    }
    const float* W; int ld = 128, k0 = 0, c0, off, st;
    if      (r < 4)  { W = msg_W + l * 35328;            st = r;      off = IMG_WI;  c0 = st * 32; }
    else if (r < 8)  { W = msg_W + l * 35328;  k0 = 128; st = r - 4;  off = IMG_WJ;  c0 = st * 32; }
    else if (r < 12) { W = upd_W + l * 16384;            st = r - 8;  off = IMG_UW;  c0 = st * 32; }
    else if (r < 16) { W = gself_W + l * 16384;          st = r - 12; off = IMG_GS;  c0 = st * 32; }
    else if (r < 20) { W = fus_W + l * 32768;            st = r - 16; off = IMG_FT;  c0 = st * 32; }
    else if (r < 24) { W = fus_W + l * 32768;  k0 = 128; st = r - 20; off = IMG_FB;  c0 = st * 32; }
    else if (r < 40) { W = cb_W1 + l * 65536;  ld = 512; st = r - 24; off = IMG_C1;  c0 = st * 32; }
    else if (r < 56) { int j = (r - 40) >> 2; W = cb_W2 + l * 65536; k0 = j * 128;
                       st = r - 40; off = IMG_C2; c0 = ((r - 40) & 3) * 32; }
    else             { W = gmean_W + l * 16384;          st = r - 56; off = IMG_GMT; c0 = st * 32; }
    ushort_t* dst = base + off + st * 4096;
    for (int e = 0; e < 16; ++e) {
        int q = threadIdx.x * 16 + e;
        int n = q >> 7, k = q & 127;
        dst[q] = f2bf(W[(size_t)(k0 + k) * ld + c0 + n]);
    }
}

// ========== preamble 2: kNN per graph (1 wave), validated logic ============
extern "C" __global__ __launch_bounds__(64)
void knn_kernel(const float* __restrict__ positions, char* __restrict__ ws)
{
    const int b = blockIdx.x, lane = threadIdx.x;
    float px = positions[b * 192 + lane * 3 + 0];
    float py = positions[b * 192 + lane * 3 + 1];
    float pz = positions[b * 192 + lane * 3 + 2];
    float* kd = (float*)(ws + WS_WEIGHTS + (size_t)b * KNN_STRIDE);
    ushort_t* ki = (ushort_t*)(kd + 1024);
    for (int n = 0; n < 64; ++n) {
        float dx = __fsub_rn(__shfl(px, n), px);
        float dy = __fsub_rn(__shfl(py, n), py);
        float dz = __fsub_rn(__shfl(pz, n), pz);
        float d2 = __fadd_rn(__fadd_rn(__fmul_rn(dx, dx), __fmul_rn(dy, dy)), __fmul_rn(dz, dz));
        if (lane == n) d2 = 1e30f;
        float sd = 0.f; int si = 0;
        for (int k = 0; k < 16; ++k) {
            float dmin = d2;
            #pragma unroll
            for (int o = 1; o < 64; o <<= 1) dmin = fminf(dmin, __shfl_xor(dmin, o));
            ull_t mask = __ballot(d2 == dmin);
            int widx = __ffsll(mask) - 1;       // lowest index on ties (= top_k)
            if (lane == widx) d2 = 1e30f;
            if (lane == k) { si = widx; sd = dmin; }
        }
        if (lane < 16) {
            kd[n * 16 + lane] = sqrtf(fmaxf(sd, 1e-12f));
            ki[n * 16 + lane] = (ushort_t)si;
        }
    }
}

// ========== main fused kernel ==============================================
// 256 threads = 4 waves; wave w owns rows w*16..w*16+15 (ALL 128 cols).
// Residual h in registers (hreg[8][4], C-layout). LDS = EXACTLY 40960 B
// -> 4 blocks/CU (16 waves/CU = 4 waves/SIMD, the VGPR-128 maximum).
// env recomputed from d in msum (identical expression to knn => bit-identical).
struct __align__(16) Smem {
    ushort_t T1[N_ * H_];   // 16384B
    ushort_t T2[N_ * H_];   // 16384B
    float d[1024];          //  4096B
    ushort_t idx[1024];     //  2048B
    char u[2048];           // union: spos(768) | {part bf16 1024, hmean 512, gvec 512}
};                          // total 40960B

// one output stage s (16 cols, col = s*16+l15), K=128: 4 B-frags from global
__device__ __forceinline__ f32x4 gemm_s(const short8 a[4], const ushort_t* __restrict__ img,
                                        int s, int l15, int quad)
{
    const ushort_t* base = img + ((s >> 1) << 12) + ((((s & 1) << 4) + l15) << 7) + quad * 8;
    short8 b0 = *(const short8*)(base);
    short8 b1 = *(const short8*)(base + 32);
    short8 b2 = *(const short8*)(base + 64);
    short8 b3 = *(const short8*)(base + 96);
    f32x4 c = {0.f, 0.f, 0.f, 0.f};
    c = __builtin_amdgcn_mfma_f32_16x16x32_bf16(a[0], b0, c, 0, 0, 0);
    c = __builtin_amdgcn_mfma_f32_16x16x32_bf16(a[1], b1, c, 0, 0, 0);
    c = __builtin_amdgcn_mfma_f32_16x16x32_bf16(a[2], b2, c, 0, 0, 0);
    c = __builtin_amdgcn_mfma_f32_16x16x32_bf16(a[3], b3, c, 0, 0, 0);
    return c;
}
__device__ __forceinline__ f32x4 gemm_s_acc(const short8 a[4], const ushort_t* __restrict__ img,
                                            int s, int l15, int quad, f32x4 c)
{
    const ushort_t* base = img + ((s >> 1) << 12) + ((((s & 1) << 4) + l15) << 7) + quad * 8;
    short8 b0 = *(const short8*)(base);
    short8 b1 = *(const short8*)(base + 32);
    short8 b2 = *(const short8*)(base + 64);
    short8 b3 = *(const short8*)(base + 96);
    c = __builtin_amdgcn_mfma_f32_16x16x32_bf16(a[0], b0, c, 0, 0, 0);
    c = __builtin_amdgcn_mfma_f32_16x16x32_bf16(a[1], b1, c, 0, 0, 0);
    c = __builtin_amdgcn_mfma_f32_16x16x32_bf16(a[2], b2, c, 0, 0, 0);
    c = __builtin_amdgcn_mfma_f32_16x16x32_bf16(a[3], b3, c, 0, 0, 0);
    return c;
}
__device__ __forceinline__ void loadA(const ushort_t* __restrict__ X, int mrow, int quad, short8 a[4]) {
    #pragma unroll
    for (int kc = 0; kc < 4; ++kc) a[kc] = *(const short8*)&X[fragoff(mrow, kc * 4 + quad)];
}

extern "C" __global__ __launch_bounds__(NT, 2)
void md17_fused_kernel(
    const float* __restrict__ positions, const int* __restrict__ atomic_numbers,
    const float* __restrict__ atom_embed, const float* __restrict__ pos_W,
    const float* __restrict__ pos_b,
    const float* __restrict__ msg_b, const float* __restrict__ upd_b,
    const float* __restrict__ g_b, const float* __restrict__ fus_b,
    const float* __restrict__ ln_g, const float* __restrict__ ln_b,
    const float* __restrict__ cb_b1, const float* __restrict__ cb_b2,
    const float* __restrict__ fo_b1,
    const float* __restrict__ fo_W2, const float* __restrict__ fo_b2,
    char* __restrict__ ws, float* __restrict__ out)
{
    __shared__ Smem sm;
    const int b = blockIdx.x;
    const int tid = threadIdx.x;
    const int wave = tid >> 6, lane = tid & 63;
    const int quad = lane >> 4, l15 = lane & 15;
    const int mrow = wave * 16 + l15;       // A-frag row (wave-owned)
    const int rbase = wave * 16 + quad * 4; // C-tile row base (wave-owned)

    const ushort_t* wimg = (const ushort_t*)ws;
    float* spos = (float*)sm.u;
    ushort_t* part = (ushort_t*)sm.u;       // [4][128] bf16 hmean partials
    float* hmean = (float*)(sm.u + 1024);
    float* gvec  = (float*)(sm.u + 1536);

    // ---- setup: kNN blob + positions ----
    {
        const char* kb = ws + WS_WEIGHTS + (size_t)b * KNN_STRIDE;
        const float* kd = (const float*)kb;
        const uint_t* ki = (const uint_t*)(kb + 4096);
        for (int t = tid; t < 1024; t += NT) sm.d[t] = kd[t];
        for (int t = tid; t < 512; t += NT) ((uint_t*)sm.idx)[t] = ki[t];
        if (tid < 192) spos[tid] = positions[b * 192 + tid];
    }
    __syncthreads();

    // ---- embeddings -> hreg (register residual, C-layout) + T1 (bf16 image) ----
    float hreg[8][4];
    {
        int types[4];
        #pragma unroll
        for (int r = 0; r < 4; ++r) types[r] = atomic_numbers[b * N_ + rbase + r];
        #pragma unroll
        for (int s = 0; s < 8; ++s) {
            int col = s * 16 + l15;
            #pragma unroll
            for (int r = 0; r < 4; ++r) {
                int row = rbase + r;
                float v;
                if (col < 32) v = atom_embed[types[r] * 32 + col];
                else {
                    int j = col - 32;
                    v = pos_b[j];
                    #pragma unroll
                    for (int c = 0; c < 3; ++c)
                        v = fmaf(spos[row * 3 + c], pos_W[c * 96 + j], v);
                }
                hreg[s][r] = v;
                sm.T1[sidx(row, col)] = f2bf(v);
            }
        }
    }

    #pragma unroll 1
    for (int l = 0; l < 4; ++l) {
        const ushort_t* wl = wimg + l * IMG_L;
        const float* mb  = msg_b + l * H_;
        const float* ub  = upd_b + l * H_;
        const float* gb  = g_b + l * H_;
        const float* fb  = fus_b + l * H_;
        const float* lg  = ln_g + l * H_;
        const float* lb  = ln_b + l * H_;
        const float* c1b = cb_b1 + l * 4 * H_;
        const float* c2b = cb_b2 + l * H_;

        // A: hmean partials from hreg (registers)
        #pragma unroll
        for (int s = 0; s < 8; ++s) {
            float p = hreg[s][0] + hreg[s][1] + hreg[s][2] + hreg[s][3];
            p += __shfl_xor(p, 16);
            p += __shfl_xor(p, 32);
            if (quad == 0) part[wave * 128 + s * 16 + l15] = f2bf(p);
        }
        __syncthreads();                                 // B1
        if (tid < H_)
            hmean[tid] = (bf2f(part[tid]) + bf2f(part[128 + tid])
                        + bf2f(part[256 + tid]) + bf2f(part[384 + tid])) * (1.0f / 64.0f);
        __syncthreads();                                 // B2

        // C: gvec GEMV (waves 0-1) ; a_h ; WI -> T1 (+mb) ; WJ -> T2
        short8 a_h[4]; loadA(sm.T1, mrow, quad, a_h);    // h image, own rows
        if (tid < H_) {
            float s = gb[tid];
            const ushort_t* wrow = wl + IMG_GMT + tid * 128;
            for (int c = 0; c < 128; c += 8) {
                short8 w = *(const short8*)(wrow + c);
                #pragma unroll
                for (int i = 0; i < 8; ++i) s = fmaf(hmean[c + i], bf2f((ushort_t)w[i]), s);
            }
            gvec[tid] = s;
        }
        #pragma unroll
        for (int s = 0; s < 8; ++s) {
            f32x4 c = gemm_s(a_h, wl + IMG_WI, s, l15, quad);
            int col = s * 16 + l15; float bv = mb[col];
            #pragma unroll
            for (int r = 0; r < 4; ++r)
                sm.T1[sidx(rbase + r, col)] = f2bf(c[r] + bv);
        }
        #pragma unroll
        for (int s = 0; s < 8; ++s) {
            f32x4 c = gemm_s(a_h, wl + IMG_WJ, s, l15, quad);
            int col = s * 16 + l15;
            #pragma unroll
            for (int r = 0; r < 4; ++r)
                sm.T2[sidx(rbase + r, col)] = f2bf(c[r]);
        }
        __syncthreads();                                 // B3 (Gm visible to all)

        // D: msum — whole wave per atom n = wave*16+g (own rows), in place in T1
        //    env recomputed from d (identical expr to knn -> bit-identical)
        {
            float ccv[8];
            #pragma unroll
            for (int j = 0; j < 8; ++j)
                ccv[j] = (float)((double)(quad * 8 + j) * (5.0 / 19.0));
            #pragma unroll 1
            for (int g = 0; g < 16; ++g) {
                int n = wave * 16 + g;
                int jv[4]; float ev[4];
                #pragma unroll
                for (int r = 0; r < 4; ++r) {
                    int k = quad * 4 + r;
                    jv[r] = sm.idx[n * 16 + k];
                    float dv = sm.d[n * 16 + k];
                    ev[r] = (dv < 5.0f) ? 0.5f * (__cosf(0.62831853071795864769f * dv) + 1.0f) : 0.0f;
                }
                float ddm = sm.d[n * 16 + l15];
                short8 arb;
                #pragma unroll
                for (int j = 0; j < 8; ++j) {
                    float t2 = ddm - ccv[j];
                    float rv = __expf(-10.0f * t2 * t2);
                    arb[j] = (short)((quad * 8 + j) < 20 ? f2bf(rv) : (ushort_t)0);
                }
                #pragma unroll
                for (int s = 0; s < 8; ++s) {
                    int col = s * 16 + l15;
                    const ushort_t* rp = wl + IMG_RW + ((s >> 1) << 10)
                                       + ((((s & 1) << 4) + l15) << 5) + quad * 8;
                    short8 brw = *(const short8*)rp;
                    f32x4 c = {0.f, 0.f, 0.f, 0.f};
                    c = __builtin_amdgcn_mfma_f32_16x16x32_bf16(arb, brw, c, 0, 0, 0);
                    float ai = bf2f(sm.T1[sidx(n, col)]);
                    float acc = 0.f;
                    #pragma unroll
                    for (int r = 0; r < 4; ++r) {
                        float gm = bf2f(sm.T2[sidx(jv[r], col)]);
                        acc = fmaf(siluf(ai + gm + c[r]), ev[r], acc);
                    }
                    acc += __shfl_xor(acc, 16);
                    acc += __shfl_xor(acc, 32);
                    if (quad == 0) sm.T1[sidx(n, col)] = f2bf(acc);
                }
            }
        }
        __syncthreads();                                 // B4 (gather done; T2 free)

        // ---- free-run region: only own rows below ----

        // F: UW(a_m)+hreg -> T2 local ; GS(a_h)+gvec -> T1 glob
        short8 a_loc[4], a_gl[4];
        {
            short8 a_m[4]; loadA(sm.T1, mrow, quad, a_m);
            #pragma unroll
            for (int s = 0; s < 8; ++s) {
                f32x4 c = gemm_s(a_m, wl + IMG_UW, s, l15, quad);
                int col = s * 16 + l15; float bv = ub[col];
                #pragma unroll
                for (int r = 0; r < 4; ++r)
                    sm.T2[sidx(rbase + r, col)] = f2bf(hreg[s][r] + siluf(c[r] + bv));
            }
            loadA(sm.T2, mrow, quad, a_loc);
            #pragma unroll
            for (int s = 0; s < 8; ++s) {
                f32x4 c = gemm_s(a_h, wl + IMG_GS, s, l15, quad);
                int col = s * 16 + l15; float gv = gvec[col];
                #pragma unroll
                for (int r = 0; r < 4; ++r)
                    sm.T1[sidx(rbase + r, col)] = f2bf(siluf(c[r] + gv));
            }
            loadA(sm.T1, mrow, quad, a_gl);
        }

        // G: fused = silu(local@FT + glob@FB + fb) -> hreg ; LN sums in regs
        float sr[4] = {0.f, 0.f, 0.f, 0.f}, qr[4] = {0.f, 0.f, 0.f, 0.f};
        #pragma unroll
        for (int s = 0; s < 8; ++s) {
            f32x4 c = gemm_s(a_loc, wl + IMG_FT, s, l15, quad);
            c = gemm_s_acc(a_gl, wl + IMG_FB, s, l15, quad, c);
            int col = s * 16 + l15; float bv = fb[col];
            #pragma unroll
            for (int r = 0; r < 4; ++r) {
                float v = siluf(c[r] + bv);
                hreg[s][r] = v;
                sr[r] += v; qr[r] += v * v;
            }
        }
        #pragma unroll
        for (int o = 1; o < 16; o <<= 1) {
            #pragma unroll
            for (int r = 0; r < 4; ++r) {
                sr[r] += __shfl_xor(sr[r], o);
                qr[r] += __shfl_xor(qr[r], o);
            }
        }

        // H: LN normalize (wave-local, from hreg) -> T1 (x-hat)
        #pragma unroll
        for (int r = 0; r < 4; ++r) {
            float mu = sr[r] * (1.0f / 128.0f);
            float var = qr[r] * (1.0f / 128.0f) - mu * mu;
            float rs = rsqrtf(var + 1e-5f);
            int row = rbase + r;
            #pragma unroll
            for (int s = 0; s < 8; ++s) {
                int col = s * 16 + l15;
                sm.T1[sidx(row, col)] = f2bf((hreg[s][r] - mu) * rs * lg[col] + lb[col]);
            }
        }

        // J: Clifford MLP, 4 K-chunks; C1 -> T2; C2 -> register acc2 (no barriers)
        {
            short8 a_x[4]; loadA(sm.T1, mrow, quad, a_x);
            f32x4 acc2[8];
            #pragma unroll
            for (int s = 0; s < 8; ++s) acc2[s] = (f32x4){0.f, 0.f, 0.f, 0.f};
            #pragma unroll 1
            for (int j = 0; j < 4; ++j) {
                #pragma unroll
                for (int s = 0; s < 8; ++s) {
                    f32x4 c = gemm_s(a_x, wl + IMG_C1 + j * 16384, s, l15, quad);
                    int col = s * 16 + l15; float bv = c1b[j * H_ + col];
                    #pragma unroll
                    for (int r = 0; r < 4; ++r)
                        sm.T2[sidx(rbase + r, col)] = f2bf(siluf(c[r] + bv));
                }
                short8 a_t[4]; loadA(sm.T2, mrow, quad, a_t);
                #pragma unroll
                for (int s = 0; s < 8; ++s)
                    acc2[s] = gemm_s_acc(a_t, wl + IMG_C2 + j * 16384, s, l15, quad, acc2[s]);
            }
            // K: h_next = fused(hreg) + acc2 + c2b -> hreg + T1 image
            #pragma unroll
            for (int s = 0; s < 8; ++s) {
                int col = s * 16 + l15; float bv = c2b[col];
                #pragma unroll
                for (int r = 0; r < 4; ++r) {
                    float v = hreg[s][r] + acc2[s][r] + bv;
                    hreg[s][r] = v;
                    sm.T1[sidx(rbase + r, col)] = f2bf(v);
                }
            }
        }
        // no layer-end barrier: next stage A reads hreg; a_h load is own-rows
    }

    // ---- head: FO -> T2 (own rows) ; barrier ; gather -> out ----
    {
        short8 a_f[4]; loadA(sm.T1, mrow, quad, a_f);
        #pragma unroll
        for (int s = 0; s < 8; ++s) {
            f32x4 c = gemm_s(a_f, wimg + IMG_FO, s, l15, quad);
            int col = s * 16 + l15; float bv = fo_b1[col];
            #pragma unroll
            for (int r = 0; r < 4; ++r)
                sm.T2[sidx(rbase + r, col)] = f2bf(siluf(c[r] + bv));
        }
    }
    __syncthreads();
    if (tid < 192) {
        int n = tid / 3, j = tid - n * 3;
        float s = fo_b2[j];
        for (int c = 0; c < H_; ++c)
            s = fmaf(bf2f(sm.T2[sidx(n, c)]), fo_W2[c * 3 + j], s);
        out[b * 192 + tid] = s;
    }
}

extern "C" void kernel_launch(void* const* d_in, const int* in_sizes, int n_in,
                              void* d_out, int out_size, void* d_ws, size_t ws_size,
                              hipStream_t stream) {
    (void)in_sizes; (void)n_in; (void)out_size; (void)ws_size;
    convert_weights<<<248, 256, 0, stream>>>(
        (const float*)d_in[5], (const float*)d_in[7], (const float*)d_in[9],
        (const float*)d_in[12], (const float*)d_in[16], (const float*)d_in[18],
        (const float*)d_in[10], (const float*)d_in[20], (ushort_t*)d_ws);
    knn_kernel<<<B_, 64, 0, stream>>>((const float*)d_in[0], (char*)d_ws);
    md17_fused_kernel<<<B_, NT, 0, stream>>>(
        (const float*)d_in[0], (const int*)d_in[1],
        (const float*)d_in[2], (const float*)d_in[3], (const float*)d_in[4],
        (const float*)d_in[6], (const float*)d_in[8],
        (const float*)d_in[11], (const float*)d_in[13],
        (const float*)d_in[14], (const float*)d_in[15],
        (const float*)d_in[17], (const float*)d_in[19],
        (const float*)d_in[21],
        (const float*)d_in[22], (const float*)d_in[23],
        (char*)d_ws, (float*)d_out);
}